// Round 1
// baseline (3076.920 us; speedup 1.0000x reference)
//
#include <hip/hip_runtime.h>
#include <math.h>

// Problem constants (from reference)
#define O_N 5000
#define T_N 20000
#define D_ 128
#define H_ 512
#define L_ 5
#define G_ 64
#define NT_ 1152   // 2H + D

// ---------------- GEMM: C = relu(A @ B + bias), fp32, 64x64 tile ----------------
// GATHER=1: A row t = concat(ov[s[t]], P[prow], ov[o[t]]) (K=384)
#define BM 64
#define BN 64
#define BK 16

template<int GATHER>
__global__ __launch_bounds__(256)
void gemm_relu_kernel(const float* __restrict__ A, int lda,
                      const float* __restrict__ B, int ldb,
                      const float* __restrict__ bias,
                      float* __restrict__ C, int ldc,
                      int M, int N, int K,
                      const float* __restrict__ rowscale,
                      const int* __restrict__ triples,
                      const float* __restrict__ ovbuf,
                      const float* __restrict__ P, int pstride,
                      int pmap_from_triples)
{
    __shared__ float As[BK][BM + 4];
    __shared__ float Bs[BK][BN + 4];
    const int bm = blockIdx.x * BM;
    const int bn = blockIdx.y * BN;
    const int tid = threadIdx.x;
    const int tx = tid & 15, ty = tid >> 4;
    const int arow = tid & 63;          // A-tile row this thread stages
    const int ak0 = (tid >> 6) << 2;    // A-tile k offset (0,4,8,12)
    const int brow = tid >> 4;          // B-tile k row (0..15)
    const int bcol = (tid & 15) << 2;   // B-tile col offset

    float acc[4][4] = {};

    const int gr = bm + arow;
    int s_idx = 0, o_idx = 0, p_row = 0;
    float rs = 1.0f;
    if (GATHER) {
        int r = (gr < M) ? gr : 0;
        s_idx = triples[r * 3 + 0];
        o_idx = triples[r * 3 + 2];
        p_row = pmap_from_triples ? triples[r * 3 + 1] : r;
    } else if (rowscale && gr < M) {
        rs = rowscale[gr];
    }

    for (int k0 = 0; k0 < K; k0 += BK) {
        float4 av = make_float4(0.f, 0.f, 0.f, 0.f);
        if (gr < M) {
            int k = k0 + ak0;
            if (GATHER) {
                if (k < 128)      av = *reinterpret_cast<const float4*>(&ovbuf[(size_t)s_idx * D_ + k]);
                else if (k < 256) av = *reinterpret_cast<const float4*>(&P[(size_t)p_row * pstride + (k - 128)]);
                else              av = *reinterpret_cast<const float4*>(&ovbuf[(size_t)o_idx * D_ + (k - 256)]);
            } else {
                av = *reinterpret_cast<const float4*>(&A[(size_t)gr * lda + k]);
                av.x *= rs; av.y *= rs; av.z *= rs; av.w *= rs;
            }
        }
        As[ak0 + 0][arow] = av.x;
        As[ak0 + 1][arow] = av.y;
        As[ak0 + 2][arow] = av.z;
        As[ak0 + 3][arow] = av.w;
        float4 bv = *reinterpret_cast<const float4*>(&B[(size_t)(k0 + brow) * ldb + bn + bcol]);
        *reinterpret_cast<float4*>(&Bs[brow][bcol]) = bv;
        __syncthreads();
        #pragma unroll
        for (int kk = 0; kk < BK; ++kk) {
            float4 a4 = *reinterpret_cast<const float4*>(&As[kk][ty << 2]);
            float4 b4 = *reinterpret_cast<const float4*>(&Bs[kk][tx << 2]);
            float a[4] = {a4.x, a4.y, a4.z, a4.w};
            float b[4] = {b4.x, b4.y, b4.z, b4.w};
            #pragma unroll
            for (int i = 0; i < 4; ++i)
                #pragma unroll
                for (int j = 0; j < 4; ++j)
                    acc[i][j] = fmaf(a[i], b[j], acc[i][j]);
        }
        __syncthreads();
    }

    float4 bb = *reinterpret_cast<const float4*>(&bias[bn + (tx << 2)]);
    float bias4[4] = {bb.x, bb.y, bb.z, bb.w};
    #pragma unroll
    for (int i = 0; i < 4; ++i) {
        int row = bm + (ty << 2) + i;
        if (row < M) {
            float4 outv;
            outv.x = fmaxf(acc[i][0] + bias4[0], 0.f);
            outv.y = fmaxf(acc[i][1] + bias4[1], 0.f);
            outv.z = fmaxf(acc[i][2] + bias4[2], 0.f);
            outv.w = fmaxf(acc[i][3] + bias4[3], 0.f);
            *reinterpret_cast<float4*>(&C[(size_t)row * ldc + bn + (tx << 2)]) = outv;
        }
    }
}

// ---------------- small kernels ----------------
__global__ void init_ov_kernel(const int* __restrict__ objs,
                               const float* __restrict__ obj_emb,
                               float* __restrict__ ov)
{
    int i = blockIdx.x * blockDim.x + threadIdx.x;
    if (i < O_N * D_) {
        int obj = objs[i >> 7];
        ov[i] = obj_emb[obj * D_ + (i & 127)];
    }
}

__global__ void count_kernel(const int* __restrict__ triples, float* __restrict__ counts)
{
    int t = blockIdx.x * blockDim.x + threadIdx.x;
    if (t < T_N) {
        atomicAdd(&counts[triples[t * 3 + 0]], 1.0f);
        atomicAdd(&counts[triples[t * 3 + 2]], 1.0f);
    }
}

__global__ void inv_counts_kernel(float* __restrict__ counts)
{
    int i = blockIdx.x * blockDim.x + threadIdx.x;
    if (i < O_N) counts[i] = 1.0f / fmaxf(counts[i], 1.0f);
}

__global__ void scatter_kernel(const float* __restrict__ new_t,
                               const int* __restrict__ triples,
                               float* __restrict__ pooled)
{
    int idx = blockIdx.x * blockDim.x + threadIdx.x;   // over T*512
    if (idx >= T_N * H_) return;
    int t = idx >> 9, d = idx & 511;
    const float* row = new_t + (size_t)t * NT_;
    atomicAdd(&pooled[(size_t)triples[t * 3 + 0] * H_ + d], row[d]);
    atomicAdd(&pooled[(size_t)triples[t * 3 + 2] * H_ + d], row[640 + d]);
}

__global__ void scores_kernel(const float* __restrict__ ov,
                              const float* __restrict__ att_w,
                              const float* __restrict__ att_b,
                              float* __restrict__ scores)
{
    int gidx = blockIdx.x * blockDim.x + threadIdx.x;
    int obj = gidx >> 6;
    int lane = threadIdx.x & 63;
    if (obj >= O_N) return;
    const float* r = ov + (size_t)obj * D_;
    float v = r[lane] * att_w[lane] + r[lane + 64] * att_w[lane + 64];
    #pragma unroll
    for (int off = 32; off; off >>= 1) v += __shfl_down(v, off);
    if (lane == 0) scores[obj] = v + att_b[0];
}

__global__ void seg_init_kernel(int* __restrict__ seg_start, int* __restrict__ seg_end)
{
    int g = threadIdx.x;
    if (g < G_) { seg_start[g] = O_N; seg_end[g] = 0; }
}

__global__ void seg_bounds_kernel(const int* __restrict__ obj_to_img,
                                  int* __restrict__ seg_start, int* __restrict__ seg_end)
{
    int i = blockIdx.x * blockDim.x + threadIdx.x;
    if (i < O_N) {
        int g = obj_to_img[i];
        atomicMin(&seg_start[g], i);
        atomicMax(&seg_end[g], i + 1);
    }
}

__global__ __launch_bounds__(256)
void seg_mz_kernel(const float* __restrict__ scores,
                   const int* __restrict__ seg_start, const int* __restrict__ seg_end,
                   float* __restrict__ segm, float* __restrict__ segz)
{
    __shared__ float red[256];
    int g = blockIdx.x, tid = threadIdx.x;
    int st = seg_start[g], en = seg_end[g];
    float lm = -1e30f;
    for (int i = st + tid; i < en; i += 256) lm = fmaxf(lm, scores[i]);
    red[tid] = lm; __syncthreads();
    for (int s = 128; s; s >>= 1) { if (tid < s) red[tid] = fmaxf(red[tid], red[tid + s]); __syncthreads(); }
    float m = red[0]; __syncthreads();
    float lz = 0.f;
    for (int i = st + tid; i < en; i += 256) lz += expf(scores[i] - m);
    red[tid] = lz; __syncthreads();
    for (int s = 128; s; s >>= 1) { if (tid < s) red[tid] += red[tid + s]; __syncthreads(); }
    if (tid == 0) { segm[g] = m; segz[g] = (red[0] > 0.f ? red[0] : 1.0f); }
}

__global__ void gvec_kernel(const float* __restrict__ scores, const float* __restrict__ ov,
                            const int* __restrict__ seg_start, const int* __restrict__ seg_end,
                            const float* __restrict__ segm, const float* __restrict__ segz,
                            float* __restrict__ gvec)
{
    int g = blockIdx.x, d = threadIdx.x;   // 128 threads
    int st = seg_start[g], en = seg_end[g];
    float m = segm[g], invz = 1.0f / segz[g];
    float acc = 0.f;
    for (int i = st; i < en; ++i)
        acc += expf(scores[i] - m) * invz * ov[(size_t)i * D_ + d];
    gvec[g * D_ + d] = acc;
}

__global__ void output_kernel(const float* __restrict__ ov, const float* __restrict__ gvec,
                              const int* __restrict__ obj_to_img, float* __restrict__ out)
{
    int idx = blockIdx.x * blockDim.x + threadIdx.x;
    if (idx >= O_N * 256) return;
    int i = idx >> 8, d = idx & 255;
    out[idx] = (d < 128) ? ov[(size_t)i * D_ + d]
                         : gvec[obj_to_img[i] * D_ + (d - 128)];
}

// ---------------- host launch ----------------
extern "C" void kernel_launch(void* const* d_in, const int* in_sizes, int n_in,
                              void* d_out, int out_size, void* d_ws, size_t ws_size,
                              hipStream_t stream)
{
    const int*   objs       = (const int*)d_in[0];
    const int*   triples    = (const int*)d_in[1];
    const int*   obj_to_img = (const int*)d_in[2];
    const float* obj_emb    = (const float*)d_in[3];
    const float* pred_emb   = (const float*)d_in[4];
    const float* n1w1       = (const float*)d_in[5];
    const float* n1b1       = (const float*)d_in[6];
    const float* n1w2       = (const float*)d_in[7];
    const float* n1b2       = (const float*)d_in[8];
    const float* n2w1       = (const float*)d_in[9];
    const float* n2b1       = (const float*)d_in[10];
    const float* n2w2       = (const float*)d_in[11];
    const float* n2b2       = (const float*)d_in[12];
    const float* att_w      = (const float*)d_in[13];
    const float* att_b      = (const float*)d_in[14];
    float* out = (float*)d_out;

    // workspace layout (floats)
    float* ws = (float*)d_ws;
    float* ov_a    = ws;                                  // O*128
    float* ov_b    = ov_a + (size_t)O_N * D_;             // O*128
    float* hidden  = ov_b + (size_t)O_N * D_;             // T*512 (reused as h2)
    float* new_t   = hidden + (size_t)T_N * H_;           // T*1152
    float* pooled  = new_t + (size_t)T_N * NT_;           // O*512
    float* inv_cnt = pooled + (size_t)O_N * H_;           // O
    float* scores  = inv_cnt + O_N;                       // O
    float* segm    = scores + O_N;                        // G
    float* segz    = segm + G_;                           // G
    float* gvec    = segz + G_;                           // G*128
    int*   seg_start = (int*)(gvec + G_ * D_);            // G
    int*   seg_end   = seg_start + G_;                    // G

    // invariant pre-compute
    hipMemsetAsync(inv_cnt, 0, O_N * sizeof(float), stream);
    init_ov_kernel<<<(O_N * D_ + 255) / 256, 256, 0, stream>>>(objs, obj_emb, ov_a);
    count_kernel<<<(T_N + 255) / 256, 256, 0, stream>>>(triples, inv_cnt);
    inv_counts_kernel<<<(O_N + 255) / 256, 256, 0, stream>>>(inv_cnt);

    float* ov_cur = ov_a;
    float* ov_nxt = ov_b;

    for (int l = 0; l < L_; ++l) {
        const float* P = (l == 0) ? pred_emb : (new_t + H_);
        int pstride = (l == 0) ? D_ : NT_;
        int pmap = (l == 0) ? 1 : 0;

        // GEMM1 (gather): hidden = relu(concat(ov[s],pv,ov[o]) @ n1w1 + b1)   [T x 384 x 512]
        gemm_relu_kernel<1><<<dim3((T_N + BM - 1) / BM, H_ / BN), 256, 0, stream>>>(
            nullptr, 0, n1w1 + (size_t)l * 3 * D_ * H_, H_, n1b1 + (size_t)l * H_,
            hidden, H_, T_N, H_, 3 * D_, nullptr,
            triples, ov_cur, P, pstride, pmap);

        // GEMM2: new_t = relu(hidden @ n1w2 + b2)                              [T x 512 x 1152]
        gemm_relu_kernel<0><<<dim3((T_N + BM - 1) / BM, NT_ / BN), 256, 0, stream>>>(
            hidden, H_, n1w2 + (size_t)l * H_ * NT_, NT_, n1b2 + (size_t)l * NT_,
            new_t, NT_, T_N, NT_, H_, nullptr,
            nullptr, nullptr, nullptr, 0, 0);

        // scatter-mean into pooled
        hipMemsetAsync(pooled, 0, (size_t)O_N * H_ * sizeof(float), stream);
        scatter_kernel<<<(T_N * H_ + 255) / 256, 256, 0, stream>>>(new_t, triples, pooled);

        // GEMM3: h2 = relu((pooled/cnt) @ n2w1 + b1)                           [O x 512 x 512]
        gemm_relu_kernel<0><<<dim3((O_N + BM - 1) / BM, H_ / BN), 256, 0, stream>>>(
            pooled, H_, n2w1 + (size_t)l * H_ * H_, H_, n2b1 + (size_t)l * H_,
            hidden, H_, O_N, H_, H_, inv_cnt,
            nullptr, nullptr, nullptr, 0, 0);

        // GEMM4: new_ov = relu(h2 @ n2w2 + b2)                                 [O x 512 x 128]
        gemm_relu_kernel<0><<<dim3((O_N + BM - 1) / BM, D_ / BN), 256, 0, stream>>>(
            hidden, H_, n2w2 + (size_t)l * H_ * D_, D_, n2b2 + (size_t)l * D_,
            ov_nxt, D_, O_N, D_, H_, nullptr,
            nullptr, nullptr, nullptr, 0, 0);

        float* tmp = ov_cur; ov_cur = ov_nxt; ov_nxt = tmp;
    }

    // graph pooling
    scores_kernel<<<(O_N * 64 + 255) / 256, 256, 0, stream>>>(ov_cur, att_w, att_b, scores);
    seg_init_kernel<<<1, G_, 0, stream>>>(seg_start, seg_end);
    seg_bounds_kernel<<<(O_N + 255) / 256, 256, 0, stream>>>(obj_to_img, seg_start, seg_end);
    seg_mz_kernel<<<G_, 256, 0, stream>>>(scores, seg_start, seg_end, segm, segz);
    gvec_kernel<<<G_, D_, 0, stream>>>(scores, ov_cur, seg_start, seg_end, segm, segz, gvec);
    output_kernel<<<(O_N * 256 + 255) / 256, 256, 0, stream>>>(ov_cur, gvec, obj_to_img, out);
}

// Round 2
// 887.201 us; speedup vs baseline: 3.4681x; 3.4681x over previous
//
#include <hip/hip_runtime.h>
#include <math.h>

#define O_N 5000
#define T_N 20000
#define D_ 128
#define H_ 512
#define L_ 5
#define G_ 64
#define NT_ 1152
#define NPRED 180

typedef unsigned short ushort_t;
typedef __attribute__((ext_vector_type(8))) __bf16 bf16x8;
typedef __attribute__((ext_vector_type(4))) float f32x4;

__device__ inline float bf2f(ushort_t u) {
    union { unsigned u32; float f; } cv; cv.u32 = ((unsigned)u) << 16; return cv.f;
}
// round-to-nearest-even fp32 -> bf16 (manual, avoids hip_bf16.h API drift)
__device__ inline ushort_t f2bf(float f) {
    union { float f; unsigned u; } cv; cv.f = f;
    unsigned x = cv.u;
    unsigned r = x + 0x7FFFu + ((x >> 16) & 1u);
    return (ushort_t)(r >> 16);
}

__device__ inline void gload16(const void* g, void* l) {
    __builtin_amdgcn_global_load_lds(
        (const __attribute__((address_space(1))) unsigned int*)g,
        (__attribute__((address_space(3))) unsigned int*)l,
        16, 0, 0);
}

// ---------------- MFMA GEMM: C = relu(A @ B^T_layout + bias) ----------------
// A: bf16 [M][K] (or gathered concat(ov[s],P[p],ov[o]) when GATHER=1, K=384)
// Bt: bf16 [N][K] (pre-transposed weights)
// 128x128 tile, 4 waves (2x2), BK=32, 16x16x32 bf16 MFMA, fp32 accum.
// LDS tiles [128 rows][32 k] bf16 with 16B-unit XOR swizzle:
//   phys_sub = logical_sub ^ ((row>>1)&3)  -> conflict-free ds_read_b128.
// global_load_lds writes linearly; the inverse swizzle is applied to the
// per-lane GLOBAL source address (guide §5 / m173 pattern).
template<int GATHER, int WRITE_F32>
__global__ __launch_bounds__(256)
void mfma_gemm(const ushort_t* __restrict__ A,
               const ushort_t* __restrict__ Bt,
               const float* __restrict__ bias,
               ushort_t* __restrict__ Cb,
               float* __restrict__ Cf,
               int M, int N, int K, int ldc,
               const int* __restrict__ triples,
               const ushort_t* __restrict__ ovb,
               const ushort_t* __restrict__ P, int pstride, int pmap)
{
    __shared__ __align__(16) ushort_t As[128 * 32];
    __shared__ __align__(16) ushort_t Bs[128 * 32];

    const int tid  = threadIdx.x;
    const int lane = tid & 63;
    const int wid  = tid >> 6;
    const int wm   = wid & 1;
    const int wn   = wid >> 1;
    const int bm   = blockIdx.x * 128;
    const int bn   = blockIdx.y * 128;

    // staging geometry: 16B unit u; issue0: u0 = wid*64+lane, issue1: +256
    const int u0 = wid * 64 + lane;
    const int u1 = u0 + 256;
    const int r0 = u0 >> 2;
    const int r1 = u1 >> 2;
    const int ks0 = (((u0 & 3) ^ ((r0 >> 1) & 3)) << 3);  // logical k elem offset
    const int ks1 = (((u1 & 3) ^ ((r1 >> 1) & 3)) << 3);

    const int ga0 = min(bm + r0, M - 1);
    const int ga1 = min(bm + r1, M - 1);
    int s0 = 0, o0 = 0, p0 = 0, s1 = 0, o1 = 0, p1 = 0;
    if (GATHER) {
        s0 = triples[ga0 * 3];  p0 = pmap ? triples[ga0 * 3 + 1] : ga0;  o0 = triples[ga0 * 3 + 2];
        s1 = triples[ga1 * 3];  p1 = pmap ? triples[ga1 * 3 + 1] : ga1;  o1 = triples[ga1 * 3 + 2];
    }
    const int gb0 = bn + r0;   // N is always a multiple of 128
    const int gb1 = bn + r1;

    // wave-uniform LDS write bases (elems)
    ushort_t* lA0 = As + wid * 512;
    ushort_t* lA1 = As + 2048 + wid * 512;
    ushort_t* lB0 = Bs + wid * 512;
    ushort_t* lB1 = Bs + 2048 + wid * 512;

    // fragment LDS read offsets (elems), swizzled — K-step invariant
    int offA[4], offB[4];
    #pragma unroll
    for (int i = 0; i < 4; ++i) {
        int ra = wm * 64 + i * 16 + (lane & 15);
        offA[i] = (ra * 4 + ((lane >> 4) ^ ((ra >> 1) & 3))) << 3;
        int rb = wn * 64 + i * 16 + (lane & 15);
        offB[i] = (rb * 4 + ((lane >> 4) ^ ((rb >> 1) & 3))) << 3;
    }

    f32x4 acc[4][4] = {};

    for (int k0 = 0; k0 < K; k0 += 32) {
        const ushort_t *gA0p, *gA1p;
        if (GATHER) {
            int k = k0 + ks0;
            gA0p = (k < 128) ? (ovb + (size_t)s0 * D_ + k)
                 : (k < 256) ? (P + (size_t)p0 * pstride + (k - 128))
                             : (ovb + (size_t)o0 * D_ + (k - 256));
            k = k0 + ks1;
            gA1p = (k < 128) ? (ovb + (size_t)s1 * D_ + k)
                 : (k < 256) ? (P + (size_t)p1 * pstride + (k - 128))
                             : (ovb + (size_t)o1 * D_ + (k - 256));
        } else {
            gA0p = A + (size_t)ga0 * K + k0 + ks0;
            gA1p = A + (size_t)ga1 * K + k0 + ks1;
        }
        gload16(gA0p, lA0);
        gload16(gA1p, lA1);
        gload16(Bt + (size_t)gb0 * K + k0 + ks0, lB0);
        gload16(Bt + (size_t)gb1 * K + k0 + ks1, lB1);
        __syncthreads();   // drains vmcnt -> LDS tiles ready

        bf16x8 av[4], bv[4];
        #pragma unroll
        for (int i = 0; i < 4; ++i) av[i] = *(const bf16x8*)(As + offA[i]);
        #pragma unroll
        for (int i = 0; i < 4; ++i) bv[i] = *(const bf16x8*)(Bs + offB[i]);
        #pragma unroll
        for (int mi = 0; mi < 4; ++mi)
            #pragma unroll
            for (int ni = 0; ni < 4; ++ni)
                acc[mi][ni] = __builtin_amdgcn_mfma_f32_16x16x32_bf16(
                    av[mi], bv[ni], acc[mi][ni], 0, 0, 0);
        __syncthreads();   // protect LDS before next stage
    }

    // epilogue: C/D layout col = lane&15, row = (lane>>4)*4 + reg  [m89/m91]
    #pragma unroll
    for (int ni = 0; ni < 4; ++ni) {
        int col = bn + wn * 64 + ni * 16 + (lane & 15);
        float bz = bias[col];
        #pragma unroll
        for (int mi = 0; mi < 4; ++mi) {
            int rowb = bm + wm * 64 + mi * 16 + ((lane >> 4) << 2);
            #pragma unroll
            for (int r = 0; r < 4; ++r) {
                int row = rowb + r;
                if (row < M) {
                    float v = fmaxf(acc[mi][ni][r] + bz, 0.0f);
                    Cb[(size_t)row * ldc + col] = f2bf(v);
                    if (WRITE_F32) Cf[(size_t)row * ldc + col] = v;
                }
            }
        }
    }
}

// ---------------- weight transpose+convert: [K][N] f32 -> [N][K] bf16 ----------------
__global__ void wt_transpose(const float* __restrict__ src, ushort_t* __restrict__ dst,
                             int K, int N)
{
    __shared__ float t[32][33];
    const int l  = blockIdx.z;
    const int n0 = blockIdx.x * 32;
    const int k0 = blockIdx.y * 32;
    const int r  = threadIdx.x >> 5;   // 0..7
    const int c  = threadIdx.x & 31;
    const float* s = src + (size_t)l * K * N;
    ushort_t*    d = dst + (size_t)l * N * K;
    #pragma unroll
    for (int j = 0; j < 4; ++j)
        t[r + j * 8][c] = s[(size_t)(k0 + r + j * 8) * N + n0 + c];
    __syncthreads();
    #pragma unroll
    for (int j = 0; j < 4; ++j)
        d[(size_t)(n0 + r + j * 8) * K + k0 + c] = f2bf(t[c][r + j * 8]);
}

// ---------------- init: ov (gathered) and pred embeddings -> bf16 ----------------
__global__ void init_embs(const int* __restrict__ objs,
                          const float* __restrict__ obj_emb,
                          const float* __restrict__ pred_emb,
                          ushort_t* __restrict__ ovb, ushort_t* __restrict__ predb)
{
    int i = blockIdx.x * blockDim.x + threadIdx.x;
    if (i < O_N * D_) ovb[i] = f2bf(obj_emb[(size_t)objs[i >> 7] * D_ + (i & 127)]);
    int j = i - O_N * D_;
    if (j >= 0 && j < NPRED * D_) predb[j] = f2bf(pred_emb[j]);
}

// ---------------- CSR build (loop-invariant, once per call) ----------------
__global__ void hist_kernel(const int* __restrict__ triples, int* __restrict__ cnt)
{
    int t = blockIdx.x * blockDim.x + threadIdx.x;
    if (t < T_N) {
        atomicAdd(&cnt[triples[t * 3]], 1);
        atomicAdd(&cnt[triples[t * 3 + 2]], 1);
    }
}

__global__ void scan_kernel(const int* __restrict__ cnt, int* __restrict__ off,
                            int* __restrict__ cursor)
{
    __shared__ int buf[256];
    __shared__ int base;
    int tid = threadIdx.x;
    if (tid == 0) base = 0;
    __syncthreads();
    for (int ch = 0; ch < O_N; ch += 256) {
        int v = (ch + tid < O_N) ? cnt[ch + tid] : 0;
        buf[tid] = v;
        __syncthreads();
        for (int s = 1; s < 256; s <<= 1) {
            int tmp = (tid >= s) ? buf[tid - s] : 0;
            __syncthreads();
            buf[tid] += tmp;
            __syncthreads();
        }
        int excl = base + buf[tid] - v;
        if (ch + tid < O_N) { off[ch + tid] = excl; cursor[ch + tid] = excl; }
        __syncthreads();
        if (tid == 0) base += buf[255];
        __syncthreads();
    }
    if (tid == 0) off[O_N] = base;
}

__global__ void fill_kernel(const int* __restrict__ triples, int* __restrict__ cursor,
                            int* __restrict__ entries)
{
    int t = blockIdx.x * blockDim.x + threadIdx.x;
    if (t < T_N) {
        int s = triples[t * 3], o = triples[t * 3 + 2];
        entries[atomicAdd(&cursor[s], 1)] = t * 2;
        entries[atomicAdd(&cursor[o], 1)] = t * 2 + 1;
    }
}

// ---------------- pooled (scatter-mean via CSR gather), 1/count fused ----------------
__global__ void pooled_kernel(const ushort_t* __restrict__ newt,
                              const int* __restrict__ entries,
                              const int* __restrict__ off,
                              ushort_t* __restrict__ pooled)
{
    int i = blockIdx.x, tid = threadIdx.x;   // 128 threads, 4 d each
    int st = off[i], en = off[i + 1];
    float a0 = 0.f, a1 = 0.f, a2 = 0.f, a3 = 0.f;
    for (int e = st; e < en; ++e) {
        int ent = entries[e];
        const ushort_t* row = newt + (size_t)(ent >> 1) * NT_ + (ent & 1) * 640 + tid * 4;
        ushort4 v = *(const ushort4*)row;
        a0 += bf2f(v.x); a1 += bf2f(v.y); a2 += bf2f(v.z); a3 += bf2f(v.w);
    }
    int c = en - st; if (c < 1) c = 1;
    float sc = 1.0f / (float)c;
    ushort4 outv;
    outv.x = f2bf(a0 * sc); outv.y = f2bf(a1 * sc);
    outv.z = f2bf(a2 * sc); outv.w = f2bf(a3 * sc);
    *(ushort4*)(pooled + (size_t)i * H_ + tid * 4) = outv;
}

// ---------------- final graph pooling (fp32, unchanged from R1) ----------------
__global__ void scores_kernel(const float* __restrict__ ov,
                              const float* __restrict__ att_w,
                              const float* __restrict__ att_b,
                              float* __restrict__ scores)
{
    int gidx = blockIdx.x * blockDim.x + threadIdx.x;
    int obj = gidx >> 6;
    int lane = threadIdx.x & 63;
    if (obj >= O_N) return;
    const float* r = ov + (size_t)obj * D_;
    float v = r[lane] * att_w[lane] + r[lane + 64] * att_w[lane + 64];
    #pragma unroll
    for (int off = 32; off; off >>= 1) v += __shfl_down(v, off);
    if (lane == 0) scores[obj] = v + att_b[0];
}

__global__ void seg_init_kernel(int* __restrict__ seg_start, int* __restrict__ seg_end)
{
    int g = threadIdx.x;
    if (g < G_) { seg_start[g] = O_N; seg_end[g] = 0; }
}

__global__ void seg_bounds_kernel(const int* __restrict__ obj_to_img,
                                  int* __restrict__ seg_start, int* __restrict__ seg_end)
{
    int i = blockIdx.x * blockDim.x + threadIdx.x;
    if (i < O_N) {
        int g = obj_to_img[i];
        atomicMin(&seg_start[g], i);
        atomicMax(&seg_end[g], i + 1);
    }
}

__global__ __launch_bounds__(256)
void seg_mz_kernel(const float* __restrict__ scores,
                   const int* __restrict__ seg_start, const int* __restrict__ seg_end,
                   float* __restrict__ segm, float* __restrict__ segz)
{
    __shared__ float red[256];
    int g = blockIdx.x, tid = threadIdx.x;
    int st = seg_start[g], en = seg_end[g];
    float lm = -1e30f;
    for (int i = st + tid; i < en; i += 256) lm = fmaxf(lm, scores[i]);
    red[tid] = lm; __syncthreads();
    for (int s = 128; s; s >>= 1) { if (tid < s) red[tid] = fmaxf(red[tid], red[tid + s]); __syncthreads(); }
    float m = red[0]; __syncthreads();
    float lz = 0.f;
    for (int i = st + tid; i < en; i += 256) lz += expf(scores[i] - m);
    red[tid] = lz; __syncthreads();
    for (int s = 128; s; s >>= 1) { if (tid < s) red[tid] += red[tid + s]; __syncthreads(); }
    if (tid == 0) { segm[g] = m; segz[g] = (red[0] > 0.f ? red[0] : 1.0f); }
}

__global__ void gvec_kernel(const float* __restrict__ scores, const float* __restrict__ ov,
                            const int* __restrict__ seg_start, const int* __restrict__ seg_end,
                            const float* __restrict__ segm, const float* __restrict__ segz,
                            float* __restrict__ gvec)
{
    int g = blockIdx.x, d = threadIdx.x;   // 128 threads
    int st = seg_start[g], en = seg_end[g];
    float m = segm[g], invz = 1.0f / segz[g];
    float acc = 0.f;
    for (int i = st; i < en; ++i)
        acc += expf(scores[i] - m) * invz * ov[(size_t)i * D_ + d];
    gvec[g * D_ + d] = acc;
}

__global__ void output_kernel(const float* __restrict__ ov, const float* __restrict__ gvec,
                              const int* __restrict__ obj_to_img, float* __restrict__ out)
{
    int idx = blockIdx.x * blockDim.x + threadIdx.x;
    if (idx >= O_N * 256) return;
    int i = idx >> 8, d = idx & 255;
    out[idx] = (d < 128) ? ov[(size_t)i * D_ + d]
                         : gvec[obj_to_img[i] * D_ + (d - 128)];
}

// ---------------- host launch ----------------
extern "C" void kernel_launch(void* const* d_in, const int* in_sizes, int n_in,
                              void* d_out, int out_size, void* d_ws, size_t ws_size,
                              hipStream_t stream)
{
    const int*   objs       = (const int*)d_in[0];
    const int*   triples    = (const int*)d_in[1];
    const int*   obj_to_img = (const int*)d_in[2];
    const float* obj_emb    = (const float*)d_in[3];
    const float* pred_emb   = (const float*)d_in[4];
    const float* n1w1       = (const float*)d_in[5];
    const float* n1b1       = (const float*)d_in[6];
    const float* n1w2       = (const float*)d_in[7];
    const float* n1b2       = (const float*)d_in[8];
    const float* n2w1       = (const float*)d_in[9];
    const float* n2b1       = (const float*)d_in[10];
    const float* n2w2       = (const float*)d_in[11];
    const float* n2b2       = (const float*)d_in[12];
    const float* att_w      = (const float*)d_in[13];
    const float* att_b      = (const float*)d_in[14];
    float* out = (float*)d_out;

    // workspace carve (256B aligned)
    char* p = (char*)d_ws;
    auto carve = [&](size_t bytes) -> char* {
        char* r = p; p += (bytes + 255) & ~(size_t)255; return r;
    };
    ushort_t* w1t     = (ushort_t*)carve((size_t)L_ * 512 * 384 * 2);
    ushort_t* w2t     = (ushort_t*)carve((size_t)L_ * 1152 * 512 * 2);
    ushort_t* w3t     = (ushort_t*)carve((size_t)L_ * 512 * 512 * 2);
    ushort_t* w4t     = (ushort_t*)carve((size_t)L_ * 128 * 512 * 2);
    ushort_t* ovbA    = (ushort_t*)carve((size_t)O_N * D_ * 2);
    ushort_t* ovbB    = (ushort_t*)carve((size_t)O_N * D_ * 2);
    ushort_t* predb   = (ushort_t*)carve((size_t)NPRED * D_ * 2);
    ushort_t* hiddenb = (ushort_t*)carve((size_t)T_N * H_ * 2);
    ushort_t* newtb   = (ushort_t*)carve((size_t)T_N * NT_ * 2);
    ushort_t* pooledb = (ushort_t*)carve((size_t)O_N * H_ * 2);
    float*    ovf     = (float*)carve((size_t)O_N * D_ * 4);
    float*    scores  = (float*)carve((size_t)O_N * 4);
    float*    segm    = (float*)carve((size_t)G_ * 4);
    float*    segz    = (float*)carve((size_t)G_ * 4);
    float*    gvec    = (float*)carve((size_t)G_ * D_ * 4);
    int*      cnt     = (int*)carve((size_t)O_N * 4);
    int*      off     = (int*)carve((size_t)(O_N + 1) * 4);
    int*      cursor  = (int*)carve((size_t)O_N * 4);
    int*      entries = (int*)carve((size_t)2 * T_N * 4);
    int*      seg_start = (int*)carve((size_t)G_ * 4);
    int*      seg_end   = (int*)carve((size_t)G_ * 4);

    // ---- once-per-call pre-compute ----
    wt_transpose<<<dim3(512 / 32, 384 / 32, L_), 256, 0, stream>>>(n1w1, w1t, 384, 512);
    wt_transpose<<<dim3(1152 / 32, 512 / 32, L_), 256, 0, stream>>>(n1w2, w2t, 512, 1152);
    wt_transpose<<<dim3(512 / 32, 512 / 32, L_), 256, 0, stream>>>(n2w1, w3t, 512, 512);
    wt_transpose<<<dim3(128 / 32, 512 / 32, L_), 256, 0, stream>>>(n2w2, w4t, 512, 128);
    init_embs<<<((O_N + NPRED) * D_ + 255) / 256, 256, 0, stream>>>(objs, obj_emb, pred_emb, ovbA, predb);
    hipMemsetAsync(cnt, 0, O_N * sizeof(int), stream);
    hist_kernel<<<(T_N + 255) / 256, 256, 0, stream>>>(triples, cnt);
    scan_kernel<<<1, 256, 0, stream>>>(cnt, off, cursor);
    fill_kernel<<<(T_N + 255) / 256, 256, 0, stream>>>(triples, cursor, entries);

    ushort_t* ovcur = ovbA;
    ushort_t* ovnxt = ovbB;

    for (int l = 0; l < L_; ++l) {
        const ushort_t* Pl = (l == 0) ? predb : (newtb + H_);
        int pstr = (l == 0) ? D_ : NT_;
        int pmap = (l == 0) ? 1 : 0;

        // GEMM1: hidden = relu(concat(ov[s],pv,ov[o]) @ n1w1 + b1)   [20000 x 384 x 512]
        mfma_gemm<1, 0><<<dim3(157, 4), 256, 0, stream>>>(
            nullptr, w1t + (size_t)l * 512 * 384, n1b1 + (size_t)l * H_,
            hiddenb, nullptr, T_N, 512, 384, H_,
            triples, ovcur, Pl, pstr, pmap);

        // GEMM2: new_t = relu(hidden @ n1w2 + b2)                    [20000 x 512 x 1152]
        mfma_gemm<0, 0><<<dim3(157, 9), 256, 0, stream>>>(
            hiddenb, w2t + (size_t)l * 1152 * 512, n1b2 + (size_t)l * NT_,
            newtb, nullptr, T_N, NT_, 512, NT_,
            nullptr, nullptr, nullptr, 0, 0);

        // scatter-mean via CSR gather (1/count fused into bf16 convert)
        pooled_kernel<<<O_N, 128, 0, stream>>>(newtb, entries, off, pooledb);

        // GEMM3: h2 = relu(pooled @ n2w1 + b1)                       [5000 x 512 x 512]
        mfma_gemm<0, 0><<<dim3(40, 4), 256, 0, stream>>>(
            pooledb, w3t + (size_t)l * 512 * 512, n2b1 + (size_t)l * H_,
            hiddenb, nullptr, O_N, 512, 512, H_,
            nullptr, nullptr, nullptr, 0, 0);

        // GEMM4: new_ov = relu(h2 @ n2w2 + b2)                       [5000 x 512 x 128]
        mfma_gemm<0, 1><<<dim3(40, 1), 256, 0, stream>>>(
            hiddenb, w4t + (size_t)l * 128 * 512, n2b2 + (size_t)l * D_,
            ovnxt, ovf, O_N, 128, 512, D_,
            nullptr, nullptr, nullptr, 0, 0);

        ushort_t* tmp = ovcur; ovcur = ovnxt; ovnxt = tmp;
    }

    // graph pooling (fp32 ov from GEMM4)
    scores_kernel<<<(O_N * 64 + 255) / 256, 256, 0, stream>>>(ovf, att_w, att_b, scores);
    seg_init_kernel<<<1, G_, 0, stream>>>(seg_start, seg_end);
    seg_bounds_kernel<<<(O_N + 255) / 256, 256, 0, stream>>>(obj_to_img, seg_start, seg_end);
    seg_mz_kernel<<<G_, 256, 0, stream>>>(scores, seg_start, seg_end, segm, segz);
    gvec_kernel<<<G_, D_, 0, stream>>>(scores, ovf, seg_start, seg_end, segm, segz, gvec);
    output_kernel<<<(O_N * 256 + 255) / 256, 256, 0, stream>>>(ovf, gvec, obj_to_img, out);
}

// Round 4
// 661.225 us; speedup vs baseline: 4.6534x; 1.3418x over previous
//
#include <hip/hip_runtime.h>
#include <math.h>

#define O_N 5000
#define T_N 20000
#define D_ 128
#define H_ 512
#define L_ 5
#define G_ 64
#define NT_ 1152
#define NPRED 180

typedef unsigned short ushort_t;
typedef __attribute__((ext_vector_type(8))) __bf16 bf16x8;
typedef __attribute__((ext_vector_type(4))) float f32x4;

__device__ inline float bf2f(ushort_t u) {
    union { unsigned u32; float f; } cv; cv.u32 = ((unsigned)u) << 16; return cv.f;
}
__device__ inline ushort_t f2bf(float f) {
    union { float f; unsigned u; } cv; cv.f = f;
    unsigned x = cv.u;
    unsigned r = x + 0x7FFFu + ((x >> 16) & 1u);
    return (ushort_t)(r >> 16);
}

__device__ inline void gload16(const void* g, void* l) {
    __builtin_amdgcn_global_load_lds(
        (const __attribute__((address_space(1))) unsigned int*)g,
        (__attribute__((address_space(3))) unsigned int*)l,
        16, 0, 0);
}

// ---------------- MFMA GEMM: C = relu(A @ Bt + bias) ----------------
// 128x128 tile, 4 waves, BK=32, 16x16x32 bf16 MFMA, fp32 accum.
// 2-phase double-buffered LDS (T3 minimal): stage(t+1) issued before
// compute(t); single vmcnt(0)+barrier per K-step.
// LDS swizzle: phys 16B-chunk = logical ^ ((row>>1)&3), applied to the
// per-lane GLOBAL source (gload_lds dest is linear) and to ds_read addrs.
// Epilogue: C tile bounced through LDS -> 16B coalesced global stores.
// Grid: 1D, XCD-bijective chunk swizzle (m204), N-fastest inside chunk
// so consecutive co-XCD blocks reuse the A-panel in their L2.
template<int GATHER, int WRITE_F32>
__global__ __launch_bounds__(256)
void mfma_gemm(const ushort_t* __restrict__ A,
               const ushort_t* __restrict__ Bt,
               const float* __restrict__ bias,
               ushort_t* __restrict__ Cb,
               float* __restrict__ Cf,
               int M, int N, int K, int ldc, int ntiles,
               const int* __restrict__ triples,
               const ushort_t* __restrict__ ovb,
               const ushort_t* __restrict__ P, int pstride, int pmap)
{
    __shared__ __align__(16) ushort_t smem[16384];   // As0|As1|Bs0|Bs1, 32 KB

    const int tid  = threadIdx.x;
    const int lane = tid & 63;
    const int wid  = tid >> 6;
    const int wm   = wid & 1;
    const int wn   = wid >> 1;

    // XCD-bijective swizzle + N-fastest decomposition
    const int nwg = gridDim.x;
    const int q = nwg >> 3, r = nwg & 7;
    const int xcd = blockIdx.x & 7, i8 = blockIdx.x >> 3;
    const int lid = (xcd < r ? xcd * (q + 1) : r * (q + 1) + (xcd - r) * q) + i8;
    const int bm = (lid / ntiles) * 128;
    const int bn = (lid % ntiles) * 128;

    // staging geometry: 16B unit u; two issues per wave per tile
    const int u0 = wid * 64 + lane;
    const int u1 = u0 + 256;
    const int r0 = u0 >> 2;
    const int r1 = u1 >> 2;
    const int ks0 = (((u0 & 3) ^ ((r0 >> 1) & 3)) << 3);   // logical k elem offset
    const int ks1 = (((u1 & 3) ^ ((r1 >> 1) & 3)) << 3);

    const int ga0 = min(bm + r0, M - 1);
    const int ga1 = min(bm + r1, M - 1);
    int s0 = 0, o0 = 0, p0 = 0, s1 = 0, o1 = 0, p1 = 0;
    if (GATHER) {
        s0 = triples[ga0 * 3];  p0 = pmap ? triples[ga0 * 3 + 1] : ga0;  o0 = triples[ga0 * 3 + 2];
        s1 = triples[ga1 * 3];  p1 = pmap ? triples[ga1 * 3 + 1] : ga1;  o1 = triples[ga1 * 3 + 2];
    }
    const int gb0 = bn + r0;
    const int gb1 = bn + r1;

    // fragment LDS read offsets (elems, buffer-relative), K-step invariant
    int offA[4], offB[4];
    #pragma unroll
    for (int i = 0; i < 4; ++i) {
        int ra = wm * 64 + i * 16 + (lane & 15);
        offA[i] = (ra * 4 + ((lane >> 4) ^ ((ra >> 1) & 3))) << 3;
        int rb = wn * 64 + i * 16 + (lane & 15);
        offB[i] = (rb * 4 + ((lane >> 4) ^ ((rb >> 1) & 3))) << 3;
    }

    auto stage = [&](int k0, int buf) {
        ushort_t* Ab = smem + buf * 4096;
        ushort_t* Bb = smem + 8192 + buf * 4096;
        const ushort_t *gA0p, *gA1p;
        if (GATHER) {
            int k = k0 + ks0;
            gA0p = (k < 128) ? (ovb + (size_t)s0 * D_ + k)
                 : (k < 256) ? (P + (size_t)p0 * pstride + (k - 128))
                             : (ovb + (size_t)o0 * D_ + (k - 256));
            k = k0 + ks1;
            gA1p = (k < 128) ? (ovb + (size_t)s1 * D_ + k)
                 : (k < 256) ? (P + (size_t)p1 * pstride + (k - 128))
                             : (ovb + (size_t)o1 * D_ + (k - 256));
        } else {
            gA0p = A + (size_t)ga0 * K + k0 + ks0;
            gA1p = A + (size_t)ga1 * K + k0 + ks1;
        }
        gload16(gA0p, Ab + wid * 512);
        gload16(gA1p, Ab + 2048 + wid * 512);
        gload16(Bt + (size_t)gb0 * K + k0 + ks0, Bb + wid * 512);
        gload16(Bt + (size_t)gb1 * K + k0 + ks1, Bb + 2048 + wid * 512);
    };

    f32x4 acc[4][4] = {};

    stage(0, 0);
    __syncthreads();

    const int nt = K >> 5;
    int cur = 0;
    for (int t = 0; t < nt; ++t) {
        if (t + 1 < nt) stage((t + 1) << 5, cur ^ 1);
        const ushort_t* Ar = smem + cur * 4096;
        const ushort_t* Br = smem + 8192 + cur * 4096;
        bf16x8 av[4], bv[4];
        #pragma unroll
        for (int i = 0; i < 4; ++i) av[i] = *(const bf16x8*)(Ar + offA[i]);
        #pragma unroll
        for (int i = 0; i < 4; ++i) bv[i] = *(const bf16x8*)(Br + offB[i]);
        #pragma unroll
        for (int mi = 0; mi < 4; ++mi)
            #pragma unroll
            for (int ni = 0; ni < 4; ++ni)
                acc[mi][ni] = __builtin_amdgcn_mfma_f32_16x16x32_bf16(
                    av[mi], bv[ni], acc[mi][ni], 0, 0, 0);
        __syncthreads();   // drains vmcnt(0): stage(t+1) landed; LDS reads done
        cur ^= 1;
    }

    if (WRITE_F32) {
        // scalar epilogue (GEMM4 only: N=128, also writes f32 copy)
        #pragma unroll
        for (int ni = 0; ni < 4; ++ni) {
            int col = bn + wn * 64 + ni * 16 + (lane & 15);
            float bz = bias[col];
            #pragma unroll
            for (int mi = 0; mi < 4; ++mi) {
                int rowb = bm + wm * 64 + mi * 16 + ((lane >> 4) << 2);
                #pragma unroll
                for (int rr = 0; rr < 4; ++rr) {
                    int row = rowb + rr;
                    if (row < M) {
                        float v = fmaxf(acc[mi][ni][rr] + bz, 0.0f);
                        Cb[(size_t)row * ldc + col] = f2bf(v);
                        Cf[(size_t)row * ldc + col] = v;
                    }
                }
            }
        }
    } else {
        // LDS-bounce epilogue: per-wave 64x64 bf16 tile, 16B coalesced stores.
        // Last loop iteration ended with __syncthreads(), so all waves are
        // done reading smem — safe to overwrite. Each wave uses its own 8 KB.
        ushort_t* cst = smem + wid * 4096;
        #pragma unroll
        for (int ni = 0; ni < 4; ++ni) {
            int col = ni * 16 + (lane & 15);
            float bz = bias[bn + wn * 64 + col];
            #pragma unroll
            for (int mi = 0; mi < 4; ++mi) {
                int rowb = mi * 16 + ((lane >> 4) << 2);
                #pragma unroll
                for (int rr = 0; rr < 4; ++rr) {
                    float v = fmaxf(acc[mi][ni][rr] + bz, 0.0f);
                    cst[(rowb + rr) * 64 + col] = f2bf(v);
                }
            }
        }
        // readback (same wave only -> no barrier): 8 rows x 8x16B per pass
        #pragma unroll
        for (int pp = 0; pp < 8; ++pp) {
            int wrow = pp * 8 + (lane >> 3);
            int grow = bm + wm * 64 + wrow;
            if (grow < M) {
                float4 v = *(const float4*)(cst + wrow * 64 + (lane & 7) * 8);
                *(float4*)(&Cb[(size_t)grow * ldc + bn + wn * 64 + (lane & 7) * 8]) = v;
            }
        }
    }
}

// ---------------- weight transpose+convert: [K][N] f32 -> [N][K] bf16 ----------------
__global__ void wt_transpose(const float* __restrict__ src, ushort_t* __restrict__ dst,
                             int K, int N)
{
    __shared__ float t[32][33];
    const int l  = blockIdx.z;
    const int n0 = blockIdx.x * 32;
    const int k0 = blockIdx.y * 32;
    const int r  = threadIdx.x >> 5;
    const int c  = threadIdx.x & 31;
    const float* s = src + (size_t)l * K * N;
    ushort_t*    d = dst + (size_t)l * N * K;
    #pragma unroll
    for (int j = 0; j < 4; ++j)
        t[r + j * 8][c] = s[(size_t)(k0 + r + j * 8) * N + n0 + c];
    __syncthreads();
    #pragma unroll
    for (int j = 0; j < 4; ++j)
        d[(size_t)(n0 + r + j * 8) * K + k0 + c] = f2bf(t[c][r + j * 8]);
}

__global__ void init_embs(const int* __restrict__ objs,
                          const float* __restrict__ obj_emb,
                          const float* __restrict__ pred_emb,
                          ushort_t* __restrict__ ovb, ushort_t* __restrict__ predb)
{
    int i = blockIdx.x * blockDim.x + threadIdx.x;
    if (i < O_N * D_) ovb[i] = f2bf(obj_emb[(size_t)objs[i >> 7] * D_ + (i & 127)]);
    int j = i - O_N * D_;
    if (j >= 0 && j < NPRED * D_) predb[j] = f2bf(pred_emb[j]);
}

// ---------------- CSR build (loop-invariant) ----------------
__global__ void hist_kernel(const int* __restrict__ triples, int* __restrict__ cnt)
{
    int t = blockIdx.x * blockDim.x + threadIdx.x;
    if (t < T_N) {
        atomicAdd(&cnt[triples[t * 3]], 1);
        atomicAdd(&cnt[triples[t * 3 + 2]], 1);
    }
}

__global__ void scan_kernel(const int* __restrict__ cnt, int* __restrict__ off,
                            int* __restrict__ cursor)
{
    __shared__ int buf[256];
    __shared__ int base;
    int tid = threadIdx.x;
    if (tid == 0) base = 0;
    __syncthreads();
    for (int ch = 0; ch < O_N; ch += 256) {
        int v = (ch + tid < O_N) ? cnt[ch + tid] : 0;
        buf[tid] = v;
        __syncthreads();
        for (int s = 1; s < 256; s <<= 1) {
            int tmp = (tid >= s) ? buf[tid - s] : 0;
            __syncthreads();
            buf[tid] += tmp;
            __syncthreads();
        }
        int excl = base + buf[tid] - v;
        if (ch + tid < O_N) { off[ch + tid] = excl; cursor[ch + tid] = excl; }
        __syncthreads();
        if (tid == 0) base += buf[255];
        __syncthreads();
    }
    if (tid == 0) off[O_N] = base;
}

__global__ void fill_kernel(const int* __restrict__ triples, int* __restrict__ cursor,
                            int* __restrict__ entries)
{
    int t = blockIdx.x * blockDim.x + threadIdx.x;
    if (t < T_N) {
        int s = triples[t * 3], o = triples[t * 3 + 2];
        entries[atomicAdd(&cursor[s], 1)] = t * 2;
        entries[atomicAdd(&cursor[o], 1)] = t * 2 + 1;
    }
}

// ---------------- scatter-mean via CSR gather, 1/count fused ----------------
__global__ void pooled_kernel(const ushort_t* __restrict__ newt,
                              const int* __restrict__ entries,
                              const int* __restrict__ off,
                              ushort_t* __restrict__ pooled)
{
    int i = blockIdx.x, tid = threadIdx.x;   // 128 threads, 4 d each
    int st = off[i], en = off[i + 1];
    float a0 = 0.f, a1 = 0.f, a2 = 0.f, a3 = 0.f;
    for (int e = st; e < en; ++e) {
        int ent = entries[e];
        const ushort_t* row = newt + (size_t)(ent >> 1) * NT_ + (ent & 1) * 640 + tid * 4;
        ushort4 v = *(const ushort4*)row;
        a0 += bf2f(v.x); a1 += bf2f(v.y); a2 += bf2f(v.z); a3 += bf2f(v.w);
    }
    int c = en - st; if (c < 1) c = 1;
    float sc = 1.0f / (float)c;
    ushort4 outv;
    outv.x = f2bf(a0 * sc); outv.y = f2bf(a1 * sc);
    outv.z = f2bf(a2 * sc); outv.w = f2bf(a3 * sc);
    *(ushort4*)(pooled + (size_t)i * H_ + tid * 4) = outv;
}

// ---------------- final graph pooling (fp32) ----------------
__global__ void scores_kernel(const float* __restrict__ ov,
                              const float* __restrict__ att_w,
                              const float* __restrict__ att_b,
                              float* __restrict__ scores)
{
    int gidx = blockIdx.x * blockDim.x + threadIdx.x;
    int obj = gidx >> 6;
    int lane = threadIdx.x & 63;
    if (obj >= O_N) return;
    const float* r = ov + (size_t)obj * D_;
    float v = r[lane] * att_w[lane] + r[lane + 64] * att_w[lane + 64];
    #pragma unroll
    for (int off = 32; off; off >>= 1) v += __shfl_down(v, off);
    if (lane == 0) scores[obj] = v + att_b[0];
}

__global__ void seg_init_kernel(int* __restrict__ seg_start, int* __restrict__ seg_end)
{
    int g = threadIdx.x;
    if (g < G_) { seg_start[g] = O_N; seg_end[g] = 0; }
}

__global__ void seg_bounds_kernel(const int* __restrict__ obj_to_img,
                                  int* __restrict__ seg_start, int* __restrict__ seg_end)
{
    int i = blockIdx.x * blockDim.x + threadIdx.x;
    if (i < O_N) {
        int g = obj_to_img[i];
        atomicMin(&seg_start[g], i);
        atomicMax(&seg_end[g], i + 1);
    }
}

__global__ __launch_bounds__(256)
void seg_mz_kernel(const float* __restrict__ scores,
                   const int* __restrict__ seg_start, const int* __restrict__ seg_end,
                   float* __restrict__ segm, float* __restrict__ segz)
{
    __shared__ float red[256];
    int g = blockIdx.x, tid = threadIdx.x;
    int st = seg_start[g], en = seg_end[g];
    float lm = -1e30f;
    for (int i = st + tid; i < en; i += 256) lm = fmaxf(lm, scores[i]);
    red[tid] = lm; __syncthreads();
    for (int s = 128; s; s >>= 1) { if (tid < s) red[tid] = fmaxf(red[tid], red[tid + s]); __syncthreads(); }
    float m = red[0]; __syncthreads();
    float lz = 0.f;
    for (int i = st + tid; i < en; i += 256) lz += expf(scores[i] - m);
    red[tid] = lz; __syncthreads();
    for (int s = 128; s; s >>= 1) { if (tid < s) red[tid] += red[tid + s]; __syncthreads(); }
    if (tid == 0) { segm[g] = m; segz[g] = (red[0] > 0.f ? red[0] : 1.0f); }
}

__global__ void gvec_kernel(const float* __restrict__ scores, const float* __restrict__ ov,
                            const int* __restrict__ seg_start, const int* __restrict__ seg_end,
                            const float* __restrict__ segm, const float* __restrict__ segz,
                            float* __restrict__ gvec)
{
    int g = blockIdx.x, d = threadIdx.x;   // 128 threads
    int st = seg_start[g], en = seg_end[g];
    float m = segm[g], invz = 1.0f / segz[g];
    float acc = 0.f;
    for (int i = st; i < en; ++i)
        acc += expf(scores[i] - m) * invz * ov[(size_t)i * D_ + d];
    gvec[g * D_ + d] = acc;
}

__global__ void output_kernel(const float* __restrict__ ov, const float* __restrict__ gvec,
                              const int* __restrict__ obj_to_img, float* __restrict__ out)
{
    int idx = blockIdx.x * blockDim.x + threadIdx.x;
    if (idx >= O_N * 256) return;
    int i = idx >> 8, d = idx & 255;
    out[idx] = (d < 128) ? ov[(size_t)i * D_ + d]
                         : gvec[obj_to_img[i] * D_ + (d - 128)];
}

// ---------------- host launch ----------------
extern "C" void kernel_launch(void* const* d_in, const int* in_sizes, int n_in,
                              void* d_out, int out_size, void* d_ws, size_t ws_size,
                              hipStream_t stream)
{
    const int*   objs       = (const int*)d_in[0];
    const int*   triples    = (const int*)d_in[1];
    const int*   obj_to_img = (const int*)d_in[2];
    const float* obj_emb    = (const float*)d_in[3];
    const float* pred_emb   = (const float*)d_in[4];
    const float* n1w1       = (const float*)d_in[5];
    const float* n1b1       = (const float*)d_in[6];
    const float* n1w2       = (const float*)d_in[7];
    const float* n1b2       = (const float*)d_in[8];
    const float* n2w1       = (const float*)d_in[9];
    const float* n2b1       = (const float*)d_in[10];
    const float* n2w2       = (const float*)d_in[11];
    const float* n2b2       = (const float*)d_in[12];
    const float* att_w      = (const float*)d_in[13];
    const float* att_b      = (const float*)d_in[14];
    float* out = (float*)d_out;

    char* p = (char*)d_ws;
    auto carve = [&](size_t bytes) -> char* {
        char* r = p; p += (bytes + 255) & ~(size_t)255; return r;
    };
    ushort_t* w1t     = (ushort_t*)carve((size_t)L_ * 512 * 384 * 2);
    ushort_t* w2t     = (ushort_t*)carve((size_t)L_ * 1152 * 512 * 2);
    ushort_t* w3t     = (ushort_t*)carve((size_t)L_ * 512 * 512 * 2);
    ushort_t* w4t     = (ushort_t*)carve((size_t)L_ * 128 * 512 * 2);
    ushort_t* ovbA    = (ushort_t*)carve((size_t)O_N * D_ * 2);
    ushort_t* ovbB    = (ushort_t*)carve((size_t)O_N * D_ * 2);
    ushort_t* predb   = (ushort_t*)carve((size_t)NPRED * D_ * 2);
    ushort_t* hiddenb = (ushort_t*)carve((size_t)T_N * H_ * 2);
    ushort_t* newtb   = (ushort_t*)carve((size_t)T_N * NT_ * 2);
    ushort_t* pooledb = (ushort_t*)carve((size_t)O_N * H_ * 2);
    float*    ovf     = (float*)carve((size_t)O_N * D_ * 4);
    float*    scores  = (float*)carve((size_t)O_N * 4);
    float*    segm    = (float*)carve((size_t)G_ * 4);
    float*    segz    = (float*)carve((size_t)G_ * 4);
    float*    gvec    = (float*)carve((size_t)G_ * D_ * 4);
    int*      cnt     = (int*)carve((size_t)O_N * 4);
    int*      off     = (int*)carve((size_t)(O_N + 1) * 4);
    int*      cursor  = (int*)carve((size_t)O_N * 4);
    int*      entries = (int*)carve((size_t)2 * T_N * 4);
    int*      seg_start = (int*)carve((size_t)G_ * 4);
    int*      seg_end   = (int*)carve((size_t)G_ * 4);

    // once-per-call pre-compute
    wt_transpose<<<dim3(512 / 32, 384 / 32, L_), 256, 0, stream>>>(n1w1, w1t, 384, 512);
    wt_transpose<<<dim3(1152 / 32, 512 / 32, L_), 256, 0, stream>>>(n1w2, w2t, 512, 1152);
    wt_transpose<<<dim3(512 / 32, 512 / 32, L_), 256, 0, stream>>>(n2w1, w3t, 512, 512);
    wt_transpose<<<dim3(128 / 32, 512 / 32, L_), 256, 0, stream>>>(n2w2, w4t, 512, 128);
    init_embs<<<((O_N + NPRED) * D_ + 255) / 256, 256, 0, stream>>>(objs, obj_emb, pred_emb, ovbA, predb);
    hipMemsetAsync(cnt, 0, O_N * sizeof(int), stream);
    hist_kernel<<<(T_N + 255) / 256, 256, 0, stream>>>(triples, cnt);
    scan_kernel<<<1, 256, 0, stream>>>(cnt, off, cursor);
    fill_kernel<<<(T_N + 255) / 256, 256, 0, stream>>>(triples, cursor, entries);

    ushort_t* ovcur = ovbA;
    ushort_t* ovnxt = ovbB;

    for (int l = 0; l < L_; ++l) {
        const ushort_t* Pl = (l == 0) ? predb : (newtb + H_);
        int pstr = (l == 0) ? D_ : NT_;
        int pmap = (l == 0) ? 1 : 0;

        // GEMM1: hidden = relu(concat(ov[s],pv,ov[o]) @ n1w1 + b1)   [20000 x 384 x 512]
        mfma_gemm<1, 0><<<157 * 4, 256, 0, stream>>>(
            nullptr, w1t + (size_t)l * 512 * 384, n1b1 + (size_t)l * H_,
            hiddenb, nullptr, T_N, 512, 384, H_, 4,
            triples, ovcur, Pl, pstr, pmap);

        // GEMM2: new_t = relu(hidden @ n1w2 + b2)                    [20000 x 512 x 1152]
        mfma_gemm<0, 0><<<157 * 9, 256, 0, stream>>>(
            hiddenb, w2t + (size_t)l * 1152 * 512, n1b2 + (size_t)l * NT_,
            newtb, nullptr, T_N, NT_, 512, NT_, 9,
            nullptr, nullptr, nullptr, 0, 0);

        // scatter-mean via CSR gather
        pooled_kernel<<<O_N, 128, 0, stream>>>(newtb, entries, off, pooledb);

        // GEMM3: h2 = relu(pooled @ n2w1 + b1)                       [5000 x 512 x 512]
        mfma_gemm<0, 0><<<40 * 4, 256, 0, stream>>>(
            pooledb, w3t + (size_t)l * 512 * 512, n2b1 + (size_t)l * H_,
            hiddenb, nullptr, O_N, 512, 512, H_, 4,
            nullptr, nullptr, nullptr, 0, 0);

        // GEMM4: new_ov = relu(h2 @ n2w2 + b2)                       [5000 x 512 x 128]
        mfma_gemm<0, 1><<<40 * 1, 256, 0, stream>>>(
            hiddenb, w4t + (size_t)l * 128 * 512, n2b2 + (size_t)l * D_,
            ovnxt, ovf, O_N, 128, 512, D_, 1,
            nullptr, nullptr, nullptr, 0, 0);

        ushort_t* tmp = ovcur; ovcur = ovnxt; ovnxt = tmp;
    }

    // graph pooling (fp32 ov from GEMM4)
    scores_kernel<<<(O_N * 64 + 255) / 256, 256, 0, stream>>>(ovf, att_w, att_b, scores);
    seg_init_kernel<<<1, G_, 0, stream>>>(seg_start, seg_end);
    seg_bounds_kernel<<<(O_N + 255) / 256, 256, 0, stream>>>(obj_to_img, seg_start, seg_end);
    seg_mz_kernel<<<G_, 256, 0, stream>>>(scores, seg_start, seg_end, segm, segz);
    gvec_kernel<<<G_, D_, 0, stream>>>(scores, ovf, seg_start, seg_end, segm, segz, gvec);
    output_kernel<<<(O_N * 256 + 255) / 256, 256, 0, stream>>>(ovf, gvec, obj_to_img, out);
}

// Round 6
// 559.375 us; speedup vs baseline: 5.5006x; 1.1821x over previous
//
#include <hip/hip_runtime.h>
#include <math.h>

#define O_N 5000
#define T_N 20000
#define D_ 128
#define H_ 512
#define L_ 5
#define G_ 64
#define NT_ 1152
#define NPRED 180

typedef unsigned short ushort_t;
typedef __attribute__((ext_vector_type(8))) __bf16 bf16x8;
typedef __attribute__((ext_vector_type(4))) float f32x4;

__device__ inline float bf2f(ushort_t u) {
    union { unsigned u32; float f; } cv; cv.u32 = ((unsigned)u) << 16; return cv.f;
}
__device__ inline ushort_t f2bf(float f) {
    union { float f; unsigned u; } cv; cv.f = f;
    unsigned x = cv.u;
    unsigned r = x + 0x7FFFu + ((x >> 16) & 1u);
    return (ushort_t)(r >> 16);
}

__device__ inline void gload16(const void* g, void* l) {
    __builtin_amdgcn_global_load_lds(
        (const __attribute__((address_space(1))) unsigned int*)g,
        (__attribute__((address_space(3))) unsigned int*)l,
        16, 0, 0);
}

// ---------------- MFMA GEMM: C = relu(A @ Bt + bias) ----------------
// 128x128 tile, 4 waves, BK=32, 16x16x32 bf16 MFMA, fp32 accum.
// Depth-2 prefetch with COUNTED vmcnt (T4): prologue stages tiles 0,1;
// each K-step: vmcnt(4)+barrier (oldest stage landed for ALL waves),
// ds_read frags, lgkmcnt(0)+barrier (all waves done reading -> WAR-safe),
// issue stage(t+2) into the just-read buffer, MFMA. vmcnt never drains
// to 0 in the main loop; final iteration peeled with vmcnt(0).
// LDS swizzle: phys 16B-chunk = logical ^ ((row>>1)&3) on global source
// (gload_lds dest is linear) and on ds_read addrs.
// Epilogue: C bounced through LDS -> 16B coalesced stores.
// Grid: 1D, XCD-bijective chunk swizzle (m204), N-fastest inside chunk.
template<int GATHER, int WRITE_F32>
__global__ __launch_bounds__(256)
void mfma_gemm(const ushort_t* __restrict__ A,
               const ushort_t* __restrict__ Bt,
               const float* __restrict__ bias,
               ushort_t* __restrict__ Cb,
               float* __restrict__ Cf,
               int M, int N, int K, int ldc, int ntiles,
               const int* __restrict__ triples,
               const ushort_t* __restrict__ ovb,
               const ushort_t* __restrict__ P, int pstride, int pmap)
{
    __shared__ __align__(16) ushort_t smem[16384];   // As0|As1|Bs0|Bs1, 32 KB

    const int tid  = threadIdx.x;
    const int lane = tid & 63;
    const int wid  = tid >> 6;
    const int wm   = wid & 1;
    const int wn   = wid >> 1;

    // XCD-bijective swizzle + N-fastest decomposition
    const int nwg = gridDim.x;
    const int q = nwg >> 3, r = nwg & 7;
    const int xcd = blockIdx.x & 7, i8 = blockIdx.x >> 3;
    const int lid = (xcd < r ? xcd * (q + 1) : r * (q + 1) + (xcd - r) * q) + i8;
    const int bm = (lid / ntiles) * 128;
    const int bn = (lid % ntiles) * 128;

    // staging geometry: 16B unit u; two issues per wave per tile
    const int u0 = wid * 64 + lane;
    const int u1 = u0 + 256;
    const int r0 = u0 >> 2;
    const int r1 = u1 >> 2;
    const int ks0 = (((u0 & 3) ^ ((r0 >> 1) & 3)) << 3);   // logical k elem offset
    const int ks1 = (((u1 & 3) ^ ((r1 >> 1) & 3)) << 3);

    const int ga0 = min(bm + r0, M - 1);
    const int ga1 = min(bm + r1, M - 1);
    int s0 = 0, o0 = 0, p0 = 0, s1 = 0, o1 = 0, p1 = 0;
    if (GATHER) {
        s0 = triples[ga0 * 3];  p0 = pmap ? triples[ga0 * 3 + 1] : ga0;  o0 = triples[ga0 * 3 + 2];
        s1 = triples[ga1 * 3];  p1 = pmap ? triples[ga1 * 3 + 1] : ga1;  o1 = triples[ga1 * 3 + 2];
    }
    const int gb0 = bn + r0;
    const int gb1 = bn + r1;

    // fragment LDS read offsets (elems, buffer-relative), K-step invariant
    int offA[4], offB[4];
    #pragma unroll
    for (int i = 0; i < 4; ++i) {
        int ra = wm * 64 + i * 16 + (lane & 15);
        offA[i] = (ra * 4 + ((lane >> 4) ^ ((ra >> 1) & 3))) << 3;
        int rb = wn * 64 + i * 16 + (lane & 15);
        offB[i] = (rb * 4 + ((lane >> 4) ^ ((rb >> 1) & 3))) << 3;
    }

    auto stage = [&](int k0, int buf) {
        ushort_t* Ab = smem + buf * 4096;
        ushort_t* Bb = smem + 8192 + buf * 4096;
        const ushort_t *gA0p, *gA1p;
        if (GATHER) {
            int k = k0 + ks0;
            gA0p = (k < 128) ? (ovb + (size_t)s0 * D_ + k)
                 : (k < 256) ? (P + (size_t)p0 * pstride + (k - 128))
                             : (ovb + (size_t)o0 * D_ + (k - 256));
            k = k0 + ks1;
            gA1p = (k < 128) ? (ovb + (size_t)s1 * D_ + k)
                 : (k < 256) ? (P + (size_t)p1 * pstride + (k - 128))
                             : (ovb + (size_t)o1 * D_ + (k - 256));
        } else {
            gA0p = A + (size_t)ga0 * K + k0 + ks0;
            gA1p = A + (size_t)ga1 * K + k0 + ks1;
        }
        gload16(gA0p, Ab + wid * 512);
        gload16(gA1p, Ab + 2048 + wid * 512);
        gload16(Bt + (size_t)gb0 * K + k0 + ks0, Bb + wid * 512);
        gload16(Bt + (size_t)gb1 * K + k0 + ks1, Bb + 2048 + wid * 512);
    };

    f32x4 acc[4][4] = {};

    const int nt = K >> 5;          // always >= 2 here (K in {384,512})
    stage(0, 0);
    stage(32, 1);                   // 8 loads/wave in flight

    int cur = 0;
    for (int t = 0; t < nt - 1; ++t) {
        // oldest stage (t) complete chip-side once every wave passes this:
        asm volatile("s_waitcnt vmcnt(4)" ::: "memory");
        __builtin_amdgcn_s_barrier();
        __builtin_amdgcn_sched_barrier(0);
        const ushort_t* Ar = smem + cur * 4096;
        const ushort_t* Br = smem + 8192 + cur * 4096;
        bf16x8 av[4], bv[4];
        #pragma unroll
        for (int i = 0; i < 4; ++i) av[i] = *(const bf16x8*)(Ar + offA[i]);
        #pragma unroll
        for (int i = 0; i < 4; ++i) bv[i] = *(const bf16x8*)(Br + offB[i]);
        // my LDS reads done; barrier => ALL waves' reads done => WAR-safe
        asm volatile("s_waitcnt lgkmcnt(0)" ::: "memory");
        __builtin_amdgcn_sched_barrier(0);
        __builtin_amdgcn_s_barrier();
        if (t + 2 < nt) stage((t + 2) << 5, cur);   // overwrite just-read buf
        #pragma unroll
        for (int mi = 0; mi < 4; ++mi)
            #pragma unroll
            for (int ni = 0; ni < 4; ++ni)
                acc[mi][ni] = __builtin_amdgcn_mfma_f32_16x16x32_bf16(
                    av[mi], bv[ni], acc[mi][ni], 0, 0, 0);
        cur ^= 1;
    }
    // final K-step: drain remaining stage fully
    {
        asm volatile("s_waitcnt vmcnt(0)" ::: "memory");
        __builtin_amdgcn_s_barrier();
        __builtin_amdgcn_sched_barrier(0);
        const ushort_t* Ar = smem + cur * 4096;
        const ushort_t* Br = smem + 8192 + cur * 4096;
        bf16x8 av[4], bv[4];
        #pragma unroll
        for (int i = 0; i < 4; ++i) av[i] = *(const bf16x8*)(Ar + offA[i]);
        #pragma unroll
        for (int i = 0; i < 4; ++i) bv[i] = *(const bf16x8*)(Br + offB[i]);
        #pragma unroll
        for (int mi = 0; mi < 4; ++mi)
            #pragma unroll
            for (int ni = 0; ni < 4; ++ni)
                acc[mi][ni] = __builtin_amdgcn_mfma_f32_16x16x32_bf16(
                    av[mi], bv[ni], acc[mi][ni], 0, 0, 0);
    }
    __syncthreads();   // all waves done with smem buffers -> epilogue reuse

    if (WRITE_F32) {
        // scalar epilogue (last-layer GEMM4 only: N=128, also writes f32)
        #pragma unroll
        for (int ni = 0; ni < 4; ++ni) {
            int col = bn + wn * 64 + ni * 16 + (lane & 15);
            float bz = bias[col];
            #pragma unroll
            for (int mi = 0; mi < 4; ++mi) {
                int rowb = bm + wm * 64 + mi * 16 + ((lane >> 4) << 2);
                #pragma unroll
                for (int rr = 0; rr < 4; ++rr) {
                    int row = rowb + rr;
                    if (row < M) {
                        float v = fmaxf(acc[mi][ni][rr] + bz, 0.0f);
                        Cb[(size_t)row * ldc + col] = f2bf(v);
                        Cf[(size_t)row * ldc + col] = v;
                    }
                }
            }
        }
    } else {
        // LDS-bounce epilogue: per-wave 64x64 bf16 tile, 16B coalesced stores
        ushort_t* cst = smem + wid * 4096;
        #pragma unroll
        for (int ni = 0; ni < 4; ++ni) {
            int col = ni * 16 + (lane & 15);
            float bz = bias[bn + wn * 64 + col];
            #pragma unroll
            for (int mi = 0; mi < 4; ++mi) {
                int rowb = mi * 16 + ((lane >> 4) << 2);
                #pragma unroll
                for (int rr = 0; rr < 4; ++rr) {
                    float v = fmaxf(acc[mi][ni][rr] + bz, 0.0f);
                    cst[(rowb + rr) * 64 + col] = f2bf(v);
                }
            }
        }
        #pragma unroll
        for (int pp = 0; pp < 8; ++pp) {
            int wrow = pp * 8 + (lane >> 3);
            int grow = bm + wm * 64 + wrow;
            if (grow < M) {
                float4 v = *(const float4*)(cst + wrow * 64 + (lane & 7) * 8);
                *(float4*)(&Cb[(size_t)grow * ldc + bn + wn * 64 + (lane & 7) * 8]) = v;
            }
        }
    }
}

// ---------------- fused precompute: 4 weight transposes + embs + cnt zero ----
// blocks [0,5440): transpose tiles (1088/layer); [5440,8030): emb convert;
// [8030,8050): zero cnt.
__global__ __launch_bounds__(256)
void precompute_kernel(const float* __restrict__ n1w1, const float* __restrict__ n1w2,
                       const float* __restrict__ n2w1, const float* __restrict__ n2w2,
                       ushort_t* __restrict__ w1t, ushort_t* __restrict__ w2t,
                       ushort_t* __restrict__ w3t, ushort_t* __restrict__ w4t,
                       const int* __restrict__ objs, const float* __restrict__ obj_emb,
                       const float* __restrict__ pred_emb,
                       ushort_t* __restrict__ ovb, ushort_t* __restrict__ predb,
                       int* __restrict__ cnt)
{
    int b = blockIdx.x;
    if (b < 5440) {
        int l = b / 1088, r = b % 1088;
        const float* src; ushort_t* dst; int K, N, n0, k0;
        if (r < 192)       { src = n1w1; dst = w1t; K = 384; N = 512;  n0 = (r % 16) * 32; k0 = (r / 16) * 32; }
        else if (r < 768)  { r -= 192;  src = n1w2; dst = w2t; K = 512; N = 1152; n0 = (r % 36) * 32; k0 = (r / 36) * 32; }
        else if (r < 1024) { r -= 768;  src = n2w1; dst = w3t; K = 512; N = 512;  n0 = (r % 16) * 32; k0 = (r / 16) * 32; }
        else               { r -= 1024; src = n2w2; dst = w4t; K = 512; N = 128;  n0 = (r % 4) * 32;  k0 = (r / 4) * 32; }
        __shared__ float t[32][33];
        const float* s = src + (size_t)l * K * N;
        ushort_t*    d = dst + (size_t)l * N * K;
        int rr = threadIdx.x >> 5, c = threadIdx.x & 31;
        #pragma unroll
        for (int j = 0; j < 4; ++j)
            t[rr + j * 8][c] = s[(size_t)(k0 + rr + j * 8) * N + n0 + c];
        __syncthreads();
        #pragma unroll
        for (int j = 0; j < 4; ++j)
            d[(size_t)(n0 + rr + j * 8) * K + k0 + c] = f2bf(t[c][rr + j * 8]);
    } else if (b < 8030) {
        int i = (b - 5440) * 256 + threadIdx.x;
        if (i < O_N * D_) ovb[i] = f2bf(obj_emb[(size_t)objs[i >> 7] * D_ + (i & 127)]);
        int j = i - O_N * D_;
        if (j >= 0 && j < NPRED * D_) predb[j] = f2bf(pred_emb[j]);
    } else {
        int i = (b - 8030) * 256 + threadIdx.x;
        if (i < O_N) cnt[i] = 0;
    }
}

// ---------------- CSR build (loop-invariant) ----------------
__global__ void hist_kernel(const int* __restrict__ triples, int* __restrict__ cnt)
{
    int t = blockIdx.x * blockDim.x + threadIdx.x;
    if (t < T_N) {
        atomicAdd(&cnt[triples[t * 3]], 1);
        atomicAdd(&cnt[triples[t * 3 + 2]], 1);
    }
}

__global__ void scan_kernel(const int* __restrict__ cnt, int* __restrict__ off,
                            int* __restrict__ cursor)
{
    __shared__ int buf[256];
    __shared__ int base;
    int tid = threadIdx.x;
    if (tid == 0) base = 0;
    __syncthreads();
    for (int ch = 0; ch < O_N; ch += 256) {
        int v = (ch + tid < O_N) ? cnt[ch + tid] : 0;
        buf[tid] = v;
        __syncthreads();
        for (int s = 1; s < 256; s <<= 1) {
            int tmp = (tid >= s) ? buf[tid - s] : 0;
            __syncthreads();
            buf[tid] += tmp;
            __syncthreads();
        }
        int excl = base + buf[tid] - v;
        if (ch + tid < O_N) { off[ch + tid] = excl; cursor[ch + tid] = excl; }
        __syncthreads();
        if (tid == 0) base += buf[255];
        __syncthreads();
    }
    if (tid == 0) off[O_N] = base;
}

__global__ void fill_kernel(const int* __restrict__ triples, int* __restrict__ cursor,
                            int* __restrict__ entries)
{
    int t = blockIdx.x * blockDim.x + threadIdx.x;
    if (t < T_N) {
        int s = triples[t * 3], o = triples[t * 3 + 2];
        entries[atomicAdd(&cursor[s], 1)] = t * 2;
        entries[atomicAdd(&cursor[o], 1)] = t * 2 + 1;
    }
}

// ---------------- scatter-mean via CSR gather, 1/count fused ----------------
__global__ void pooled_kernel(const ushort_t* __restrict__ newt,
                              const int* __restrict__ entries,
                              const int* __restrict__ off,
                              ushort_t* __restrict__ pooled)
{
    int i = blockIdx.x, tid = threadIdx.x;   // 128 threads, 4 d each
    int st = off[i], en = off[i + 1];
    float a0 = 0.f, a1 = 0.f, a2 = 0.f, a3 = 0.f;
    for (int e = st; e < en; ++e) {
        int ent = entries[e];
        const ushort_t* row = newt + (size_t)(ent >> 1) * NT_ + (ent & 1) * 640 + tid * 4;
        ushort4 v = *(const ushort4*)row;
        a0 += bf2f(v.x); a1 += bf2f(v.y); a2 += bf2f(v.z); a3 += bf2f(v.w);
    }
    int c = en - st; if (c < 1) c = 1;
    float sc = 1.0f / (float)c;
    ushort4 outv;
    outv.x = f2bf(a0 * sc); outv.y = f2bf(a1 * sc);
    outv.z = f2bf(a2 * sc); outv.w = f2bf(a3 * sc);
    *(ushort4*)(pooled + (size_t)i * H_ + tid * 4) = outv;
}

// ---------------- final graph pooling ----------------
__global__ void scores_kernel(const float* __restrict__ ov,
                              const float* __restrict__ att_w,
                              const float* __restrict__ att_b,
                              float* __restrict__ scores)
{
    int gidx = blockIdx.x * blockDim.x + threadIdx.x;
    int obj = gidx >> 6;
    int lane = threadIdx.x & 63;
    if (obj >= O_N) return;
    const float* r = ov + (size_t)obj * D_;
    float v = r[lane] * att_w[lane] + r[lane + 64] * att_w[lane + 64];
    #pragma unroll
    for (int off = 32; off; off >>= 1) v += __shfl_down(v, off);
    if (lane == 0) scores[obj] = v + att_b[0];
}

// one block per image: binary-search bounds in SORTED obj_to_img,
// then max / sum(exp) / weighted ov-sum, all block-local.
__global__ __launch_bounds__(256)
void seg_gvec_kernel(const float* __restrict__ scores, const float* __restrict__ ovf,
                     const int* __restrict__ obj_to_img, float* __restrict__ gvec)
{
    __shared__ float red[256];
    __shared__ float sm, sz;
    int g = blockIdx.x, tid = threadIdx.x;
    int lo = 0, hi = O_N;
    while (lo < hi) { int mid = (lo + hi) >> 1; if (obj_to_img[mid] < g) lo = mid + 1; else hi = mid; }
    int st = lo;
    hi = O_N;
    while (lo < hi) { int mid = (lo + hi) >> 1; if (obj_to_img[mid] <= g) lo = mid + 1; else hi = mid; }
    int en = lo;

    float lm = -1e30f;
    for (int i = st + tid; i < en; i += 256) lm = fmaxf(lm, scores[i]);
    red[tid] = lm; __syncthreads();
    for (int s = 128; s; s >>= 1) { if (tid < s) red[tid] = fmaxf(red[tid], red[tid + s]); __syncthreads(); }
    if (tid == 0) sm = red[0];
    __syncthreads();
    float m = sm;

    float lz = 0.f;
    for (int i = st + tid; i < en; i += 256) lz += expf(scores[i] - m);
    red[tid] = lz; __syncthreads();
    for (int s = 128; s; s >>= 1) { if (tid < s) red[tid] += red[tid + s]; __syncthreads(); }
    if (tid == 0) sz = fmaxf(red[0], 1e-30f);
    __syncthreads();
    float invz = 1.0f / sz;

    int d = tid & 127, half = tid >> 7;
    float acc = 0.f;
    for (int i = st + half; i < en; i += 2)
        acc += expf(scores[i] - m) * ovf[(size_t)i * D_ + d];
    red[tid] = acc; __syncthreads();
    if (tid < 128) gvec[(size_t)g * D_ + tid] = (red[tid] + red[tid + 128]) * invz;
}

__global__ void output_kernel(const float* __restrict__ ov, const float* __restrict__ gvec,
                              const int* __restrict__ obj_to_img, float* __restrict__ out)
{
    int idx = blockIdx.x * blockDim.x + threadIdx.x;
    if (idx >= O_N * 256) return;
    int i = idx >> 8, d = idx & 255;
    out[idx] = (d < 128) ? ov[(size_t)i * D_ + d]
                         : gvec[obj_to_img[i] * D_ + (d - 128)];
}

// ---------------- host launch ----------------
extern "C" void kernel_launch(void* const* d_in, const int* in_sizes, int n_in,
                              void* d_out, int out_size, void* d_ws, size_t ws_size,
                              hipStream_t stream)
{
    const int*   objs       = (const int*)d_in[0];
    const int*   triples    = (const int*)d_in[1];
    const int*   obj_to_img = (const int*)d_in[2];
    const float* obj_emb    = (const float*)d_in[3];
    const float* pred_emb   = (const float*)d_in[4];
    const float* n1w1       = (const float*)d_in[5];
    const float* n1b1       = (const float*)d_in[6];
    const float* n1w2       = (const float*)d_in[7];
    const float* n1b2       = (const float*)d_in[8];
    const float* n2w1       = (const float*)d_in[9];
    const float* n2b1       = (const float*)d_in[10];
    const float* n2w2       = (const float*)d_in[11];
    const float* n2b2       = (const float*)d_in[12];
    const float* att_w      = (const float*)d_in[13];
    const float* att_b      = (const float*)d_in[14];
    float* out = (float*)d_out;

    char* p = (char*)d_ws;
    auto carve = [&](size_t bytes) -> char* {
        char* r = p; p += (bytes + 255) & ~(size_t)255; return r;
    };
    ushort_t* w1t     = (ushort_t*)carve((size_t)L_ * 512 * 384 * 2);
    ushort_t* w2t     = (ushort_t*)carve((size_t)L_ * 1152 * 512 * 2);
    ushort_t* w3t     = (ushort_t*)carve((size_t)L_ * 512 * 512 * 2);
    ushort_t* w4t     = (ushort_t*)carve((size_t)L_ * 128 * 512 * 2);
    ushort_t* ovbA    = (ushort_t*)carve((size_t)O_N * D_ * 2);
    ushort_t* ovbB    = (ushort_t*)carve((size_t)O_N * D_ * 2);
    ushort_t* predb   = (ushort_t*)carve((size_t)NPRED * D_ * 2);
    ushort_t* hiddenb = (ushort_t*)carve((size_t)T_N * H_ * 2);
    ushort_t* newtb   = (ushort_t*)carve((size_t)T_N * NT_ * 2);
    ushort_t* pooledb = (ushort_t*)carve((size_t)O_N * H_ * 2);
    float*    ovf     = (float*)carve((size_t)O_N * D_ * 4);
    float*    scores  = (float*)carve((size_t)O_N * 4);
    float*    gvec    = (float*)carve((size_t)G_ * D_ * 4);
    int*      cnt     = (int*)carve((size_t)O_N * 4);
    int*      off     = (int*)carve((size_t)(O_N + 1) * 4);
    int*      cursor  = (int*)carve((size_t)O_N * 4);
    int*      entries = (int*)carve((size_t)2 * T_N * 4);

    // once-per-call pre-compute (fused) + CSR build
    precompute_kernel<<<8050, 256, 0, stream>>>(
        n1w1, n1w2, n2w1, n2w2, w1t, w2t, w3t, w4t,
        objs, obj_emb, pred_emb, ovbA, predb, cnt);
    hist_kernel<<<(T_N + 255) / 256, 256, 0, stream>>>(triples, cnt);
    scan_kernel<<<1, 256, 0, stream>>>(cnt, off, cursor);
    fill_kernel<<<(T_N + 255) / 256, 256, 0, stream>>>(triples, cursor, entries);

    ushort_t* ovcur = ovbA;
    ushort_t* ovnxt = ovbB;

    for (int l = 0; l < L_; ++l) {
        const ushort_t* Pl = (l == 0) ? predb : (newtb + H_);
        int pstr = (l == 0) ? D_ : NT_;
        int pmap = (l == 0) ? 1 : 0;

        // GEMM1: hidden = relu(concat(ov[s],pv,ov[o]) @ n1w1 + b1)   [20000 x 384 x 512]
        mfma_gemm<1, 0><<<157 * 4, 256, 0, stream>>>(
            nullptr, w1t + (size_t)l * 512 * 384, n1b1 + (size_t)l * H_,
            hiddenb, nullptr, T_N, 512, 384, H_, 4,
            triples, ovcur, Pl, pstr, pmap);

        // GEMM2: new_t = relu(hidden @ n1w2 + b2)                    [20000 x 512 x 1152]
        mfma_gemm<0, 0><<<157 * 9, 256, 0, stream>>>(
            hiddenb, w2t + (size_t)l * 1152 * 512, n1b2 + (size_t)l * NT_,
            newtb, nullptr, T_N, NT_, 512, NT_, 9,
            nullptr, nullptr, nullptr, 0, 0);

        // scatter-mean via CSR gather
        pooled_kernel<<<O_N, 128, 0, stream>>>(newtb, entries, off, pooledb);

        // GEMM3: h2 = relu(pooled @ n2w1 + b1)                       [5000 x 512 x 512]
        mfma_gemm<0, 0><<<40 * 4, 256, 0, stream>>>(
            pooledb, w3t + (size_t)l * 512 * 512, n2b1 + (size_t)l * H_,
            hiddenb, nullptr, O_N, 512, 512, H_, 4,
            nullptr, nullptr, nullptr, 0, 0);

        // GEMM4: new_ov = relu(h2 @ n2w2 + b2)                       [5000 x 512 x 128]
        if (l < L_ - 1) {
            mfma_gemm<0, 0><<<40 * 1, 256, 0, stream>>>(
                hiddenb, w4t + (size_t)l * 128 * 512, n2b2 + (size_t)l * D_,
                ovnxt, nullptr, O_N, 128, 512, D_, 1,
                nullptr, nullptr, nullptr, 0, 0);
        } else {
            mfma_gemm<0, 1><<<40 * 1, 256, 0, stream>>>(
                hiddenb, w4t + (size_t)l * 128 * 512, n2b2 + (size_t)l * D_,
                ovnxt, ovf, O_N, 128, 512, D_, 1,
                nullptr, nullptr, nullptr, 0, 0);
        }

        ushort_t* tmp = ovcur; ovcur = ovnxt; ovnxt = tmp;
    }

    // graph pooling (fp32 ov from last GEMM4)
    scores_kernel<<<(O_N * 64 + 255) / 256, 256, 0, stream>>>(ovf, att_w, att_b, scores);
    seg_gvec_kernel<<<G_, 256, 0, stream>>>(scores, ovf, obj_to_img, gvec);
    output_kernel<<<(O_N * 256 + 255) / 256, 256, 0, stream>>>(ovf, gvec, obj_to_img, out);
}